// Round 1
// baseline (55849.908 us; speedup 1.0000x reference)
//
#include <hip/hip_runtime.h>
#include <cstdint>
#include <cstddef>

// Problem dims (fixed): B=64, T=512, D=1024, U=1024
#define NB 64
#define NT 512
#define ND 1024
#define NU 1024

typedef short s16x8 __attribute__((ext_vector_type(8)));   // 8 bf16 (bit pattern)
typedef float f32x4 __attribute__((ext_vector_type(4)));
typedef unsigned short u16;

__device__ __forceinline__ u16 f2bf(float f) {
  unsigned int u = __float_as_uint(f);
  u += 0x7fffu + ((u >> 16) & 1u);           // round-to-nearest-even
  return (u16)(u >> 16);
}
__device__ __forceinline__ float bf2f(u16 s) {
  return __uint_as_float(((unsigned int)s) << 16);
}
__device__ __forceinline__ float hsig(float x) {
  return fminf(fmaxf(0.2f * x + 0.5f, 0.0f), 1.0f);
}
__device__ __forceinline__ f32x4 mfma16(s16x8 a, s16x8 b, f32x4 c) {
  return __builtin_amdgcn_mfma_f32_16x16x32_bf16(a, b, c, 0, 0, 0);
}

// ---------------------------------------------------------------------------
// Kernel 1: xW = x_flat(32768x1024) @ W(1024x4096), bf16 MFMA, out bf16.
// Output layout: XW[((t*64)+b)*4096 + col]  (t-major slabs for the loop phase)
// ---------------------------------------------------------------------------
__global__ __launch_bounds__(256) void xw_gemm(const float* __restrict__ X,
                                               const float* __restrict__ W,
                                               u16* __restrict__ XW) {
  __shared__ u16 Al[128][72];   // A rows x k (pad 8)
  __shared__ u16 Bl[128][72];   // B transposed: [n][k]
  const int tid = threadIdx.x;
  const int lane = tid & 63;
  const int wv = tid >> 6;
  const int m0 = (blockIdx.x >> 5) * 128;   // 256 row-bands
  const int n0 = (blockIdx.x & 31) * 128;   // 32 col-bands
  f32x4 acc[4][4];
#pragma unroll
  for (int i = 0; i < 4; ++i)
#pragma unroll
    for (int j = 0; j < 4; ++j) acc[i][j] = (f32x4){0.f, 0.f, 0.f, 0.f};

  for (int kt = 0; kt < 1024; kt += 64) {
    {  // stage A: 128 rows x 64 k
      const int r = tid >> 1, hh = (tid & 1) * 32;
      const float* src = X + (size_t)(m0 + r) * 1024 + kt + hh;
      u16* dst = &Al[r][hh];
#pragma unroll
      for (int j = 0; j < 8; ++j) {
        float4 v = ((const float4*)src)[j];
        dst[j * 4 + 0] = f2bf(v.x); dst[j * 4 + 1] = f2bf(v.y);
        dst[j * 4 + 2] = f2bf(v.z); dst[j * 4 + 3] = f2bf(v.w);
      }
    }
    {  // stage B transposed: 64 k-rows x 128 n  -> Bl[n][k]
      const int kr = tid >> 2, q = (tid & 3) * 32;
      const float* src = W + (size_t)(kt + kr) * 4096 + n0 + q;
#pragma unroll
      for (int j = 0; j < 8; ++j) {
        float4 v = ((const float4*)src)[j];
        const int n = q + j * 4;
        Bl[n + 0][kr] = f2bf(v.x); Bl[n + 1][kr] = f2bf(v.y);
        Bl[n + 2][kr] = f2bf(v.z); Bl[n + 3][kr] = f2bf(v.w);
      }
    }
    __syncthreads();
    const int wm = (wv >> 1) * 64, wn = (wv & 1) * 64;
    const int row = lane & 15, kq = (lane >> 4) * 8;
#pragma unroll
    for (int ks = 0; ks < 2; ++ks) {
      s16x8 af[4], bq[4];
#pragma unroll
      for (int i = 0; i < 4; ++i) af[i] = *(const s16x8*)&Al[wm + i * 16 + row][ks * 32 + kq];
#pragma unroll
      for (int j = 0; j < 4; ++j) bq[j] = *(const s16x8*)&Bl[wn + j * 16 + row][ks * 32 + kq];
#pragma unroll
      for (int i = 0; i < 4; ++i)
#pragma unroll
        for (int j = 0; j < 4; ++j) acc[i][j] = mfma16(af[i], bq[j], acc[i][j]);
    }
    __syncthreads();
  }
  // epilogue: C/D layout col=lane&15, row=(lane>>4)*4+q  [m89-verified]
  const int wm = (wv >> 1) * 64, wn = (wv & 1) * 64;
  const int col16 = lane & 15, rq = (lane >> 4) * 4;
#pragma unroll
  for (int i = 0; i < 4; ++i)
#pragma unroll
    for (int j = 0; j < 4; ++j)
#pragma unroll
      for (int q = 0; q < 4; ++q) {
        const int m = m0 + wm + i * 16 + rq + q;       // m = b*512 + t
        const int n = n0 + wn + j * 16 + col16;
        const int t = m & 511, b = m >> 9;
        XW[((size_t)(t * 64 + b)) * 4096 + n] = f2bf(acc[i][j][q]);
      }
}

// ---------------------------------------------------------------------------
// Kernel 2: init broadcast buffers from h0/c0
// ---------------------------------------------------------------------------
__global__ void init_comm(const float* __restrict__ h0, const float* __restrict__ c0,
                          u16* hbuf, u16* cbuf0) {
  const int i = blockIdx.x * 256 + threadIdx.x;   // 64*1024 / 256 blocks
  hbuf[i] = f2bf(h0[i]);
  cbuf0[i] = f2bf(c0[i]);
}

// ---------------------------------------------------------------------------
// Grid barrier: monotonic counter, zeroed by hipMemsetAsync each launch.
// ---------------------------------------------------------------------------
__device__ __forceinline__ void gbar(unsigned int* bar, unsigned int target) {
  __threadfence();
  __syncthreads();
  if (threadIdx.x == 0) {
    __atomic_fetch_add(bar, 1u, __ATOMIC_RELAXED);
    while (__atomic_load_n(bar, __ATOMIC_RELAXED) < target) __builtin_amdgcn_s_sleep(2);
  }
  __syncthreads();
  __threadfence();
}

// ---------------------------------------------------------------------------
// Kernel 3: persistent recurrence. 256 blocks (1/CU) x 256 threads.
// Block owns 8 u-columns x 32 batch rows. LDS holds its weight slice (bf16):
//   cols 0-15:  R cols [i u0..7 | f u0..7]     (z tile 0)
//   cols 16-31: R cols [c u0..7 | o u0..7]     (z tile 1)
//   cols 32-47: [Pi u0..7 | Pf u0..7]          (P tile, A = c_prev)
//   cols 48-55: Po u0..7                       (phase-2 tile cols 0-7, A = c_new)
//   cols 56-63: proj u0..7                     (phase-2 tile cols 8-15, A = tanh(c_new))
// Cell state c is f32 in registers (1 elem/thread). h/c/tanh(c) broadcast bf16.
// ---------------------------------------------------------------------------
#define WLDS_B   (64 * 1032 * 2)       // 132096
#define ZOFF     WLDS_B
#define POFF     (ZOFF + 32 * 33 * 4)  // 136320
#define OOFF     (POFF + 32 * 17 * 4)  // 138496
#define SMEM_B   (OOFF + 32 * 17 * 4)  // 140672

__global__ __launch_bounds__(256, 1) void lstm_loop(
    const float* __restrict__ rec, const float* __restrict__ peep,
    const float* __restrict__ projw, const float* __restrict__ bias,
    const float* __restrict__ x, const u16* __restrict__ xw,
    float* __restrict__ out,
    u16* hbuf, u16* cbuf0, u16* cbuf1, u16* thbuf,
    unsigned int* bar, const float* __restrict__ c0) {
  extern __shared__ char smem[];
  u16 (*wlds)[1032] = (u16(*)[1032])smem;
  float (*zlds)[33] = (float(*)[33])(smem + ZOFF);
  float (*plds)[17] = (float(*)[17])(smem + POFF);
  float (*olds)[17] = (float(*)[17])(smem + OOFF);

  const int tid = threadIdx.x;
  const int lane = tid & 63;
  const int wv = tid >> 6;
  const int ugrp = blockIdx.x >> 1;
  const int rh = blockIdx.x & 1;
  const int row0 = rh * 32;
  const int u0 = ugrp * 8;

  // ---- stage weight slice into LDS (once) ----
  for (int run = wv; run < 8; run += 4) {
    const int c = run * 8 + (lane & 7);
    const float* sp; int stride, scol;
    if (c < 32)      { sp = rec;   stride = 4096; scol = (c >> 3) * 1024 + u0 + (c & 7); }
    else if (c < 48) { sp = peep;  stride = 3072; scol = ((c - 32) >> 3) * 1024 + u0 + (c & 7); }
    else if (c < 56) { sp = peep;  stride = 3072; scol = 2048 + u0 + (c & 7); }
    else             { sp = projw; stride = 1024; scol = u0 + (c - 56); }
    const int kr = lane >> 3;
    for (int k0 = 0; k0 < 1024; k0 += 8)
      wlds[c][k0 + kr] = f2bf(sp[(size_t)(k0 + kr) * stride + scol]);
  }

  // per-thread (row,u) mapping for gate assembly + register c-state
  const int r = tid >> 3;        // 0..31 local row
  const int ul = tid & 7;        // 0..7 local u
  const int brow = row0 + r;     // global batch row
  const int u = u0 + ul;         // global unit
  const float b_i = bias[u], b_f = bias[1024 + u], b_c = bias[2048 + u], b_o = bias[3072 + u];
  float cst = c0[brow * 1024 + u];

  __syncthreads();

  unsigned int nbar = 0;
  const int rt = (wv < 2) ? wv : (wv - 2);
  const int fcol = lane & 15;
  const int kofs = (lane >> 4) * 8;

  for (int t = 0; t < NT; ++t) {
    const u16* cprev = (t & 1) ? cbuf1 : cbuf0;
    u16* cnew = (t & 1) ? cbuf0 : cbuf1;
    float zo_reg;

    // ===== phase 1: z = h@R (+xW+bias), peephole c@Pi/Pf, c_new =====
    {
      f32x4 accA = {0.f, 0.f, 0.f, 0.f}, accB = {0.f, 0.f, 0.f, 0.f};
      const int arow = row0 + rt * 16 + fcol;
      if (wv < 2) {
        const u16* ap = hbuf + arow * 1024 + kofs;
        const u16* bp0 = &wlds[fcol][kofs];
        const u16* bp1 = &wlds[16 + fcol][kofs];
#pragma unroll 8
        for (int kt = 0; kt < 32; ++kt) {
          s16x8 a  = *(const s16x8*)(ap + kt * 32);
          s16x8 b0 = *(const s16x8*)(bp0 + kt * 32);
          s16x8 b1 = *(const s16x8*)(bp1 + kt * 32);
          accA = mfma16(a, b0, accA);
          accB = mfma16(a, b1, accB);
        }
      } else {
        const u16* ap = cprev + arow * 1024 + kofs;
        const u16* bp = &wlds[32 + fcol][kofs];
#pragma unroll 8
        for (int kt = 0; kt < 32; ++kt) {
          s16x8 a = *(const s16x8*)(ap + kt * 32);
          s16x8 b = *(const s16x8*)(bp + kt * 32);
          accA = mfma16(a, b, accA);
        }
      }
      const int srow = rt * 16 + (lane >> 4) * 4;
      if (wv < 2) {
#pragma unroll
        for (int q = 0; q < 4; ++q) {
          zlds[srow + q][fcol] = accA[q];
          zlds[srow + q][16 + fcol] = accB[q];
        }
      } else {
#pragma unroll
        for (int q = 0; q < 4; ++q) plds[srow + q][fcol] = accA[q];
      }
    }
    __syncthreads();
    {
      const u16* xr = xw + ((size_t)t * 64 + brow) * 4096;
      const float zi = zlds[r][ul]      + bf2f(xr[u])        + b_i + plds[r][ul];
      const float zf = zlds[r][8 + ul]  + bf2f(xr[1024 + u]) + b_f + plds[r][8 + ul];
      const float zc = zlds[r][16 + ul] + bf2f(xr[2048 + u]) + b_c;
      zo_reg         = zlds[r][24 + ul] + bf2f(xr[3072 + u]) + b_o;
      const float ig = hsig(zi), fg = hsig(zf);
      cst = fg * cst + ig * tanhf(zc);
      const float th = tanhf(cst);
      cnew[brow * 1024 + u] = f2bf(cst);
      thbuf[brow * 1024 + u] = f2bf(th);
    }
    ++nbar; gbar(bar, nbar * 256u);   // c_new / tanh(c_new) published

    // ===== phase 2: o = hsig(zo + c_new@Po); h = o*(tanh(c_new)@proj + x_t) =====
    {
      f32x4 acc = {0.f, 0.f, 0.f, 0.f};
      const int prt = wv & 1;
      const int arow = row0 + prt * 16 + fcol;
      const u16* ap = ((wv < 2) ? (const u16*)cnew : (const u16*)thbuf) + arow * 1024 + kofs;
      const u16* bp = &wlds[48 + fcol][kofs];   // cols 0-7 Po, 8-15 proj
#pragma unroll 8
      for (int kt = 0; kt < 32; ++kt) {
        s16x8 a = *(const s16x8*)(ap + kt * 32);
        s16x8 b = *(const s16x8*)(bp + kt * 32);
        acc = mfma16(a, b, acc);
      }
      const int srow = prt * 16 + (lane >> 4) * 4;
      if (wv < 2) {        // Po result valid on cols 0-7 (A = c_new)
        if (fcol < 8) {
#pragma unroll
          for (int q = 0; q < 4; ++q) olds[srow + q][fcol] = acc[q];
        }
      } else {             // proj result valid on cols 8-15 (A = tanh(c_new))
        if (fcol >= 8) {
#pragma unroll
          for (int q = 0; q < 4; ++q) olds[srow + q][fcol] = acc[q];
        }
      }
    }
    __syncthreads();
    {
      const float og = hsig(zo_reg + olds[r][ul]);
      const size_t xo = (size_t)brow * (512 * 1024) + (size_t)t * 1024 + u;
      const float pv = olds[r][8 + ul] + x[xo];
      const float hv = og * pv;
      out[xo] = hv;
      hbuf[brow * 1024 + u] = f2bf(hv);
    }
    ++nbar; gbar(bar, nbar * 256u);   // h published
  }
}

// ---------------------------------------------------------------------------
// Host launcher
// ---------------------------------------------------------------------------
extern "C" void kernel_launch(void* const* d_in, const int* in_sizes, int n_in,
                              void* d_out, int out_size, void* d_ws, size_t ws_size,
                              hipStream_t stream) {
  const float* x    = (const float*)d_in[0];
  const float* h0   = (const float*)d_in[1];
  const float* c0   = (const float*)d_in[2];
  const float* W    = (const float*)d_in[3];
  const float* R    = (const float*)d_in[4];
  const float* P    = (const float*)d_in[5];
  const float* PRJ  = (const float*)d_in[6];
  const float* bias = (const float*)d_in[7];
  float* out = (float*)d_out;
  char* ws = (char*)d_ws;

  const size_t XW_BYTES = (size_t)32768 * 4096 * 2;   // 268435456
  size_t off = XW_BYTES;
  u16* xw   = (u16*)ws;
  u16* hbuf = (u16*)(ws + off); off += 131072;
  u16* cb0  = (u16*)(ws + off); off += 131072;
  u16* cb1  = (u16*)(ws + off); off += 131072;
  u16* thb  = (u16*)(ws + off); off += 131072;
  unsigned int* bar = (unsigned int*)(ws + off); off += 4096;
  if (ws_size < off) return;   // insufficient workspace -> visible failure

  (void)hipFuncSetAttribute(reinterpret_cast<const void*>(&lstm_loop),
                            hipFuncAttributeMaxDynamicSharedMemorySize, 160 * 1024);

  hipMemsetAsync(bar, 0, 4096, stream);
  hipLaunchKernelGGL(init_comm, dim3(256), dim3(256), 0, stream, h0, c0, hbuf, cb0);
  hipLaunchKernelGGL(xw_gemm, dim3(8192), dim3(256), 0, stream, x, W, xw);

  void* args[13];
  args[0] = (void*)&R;    args[1] = (void*)&P;    args[2] = (void*)&PRJ;
  args[3] = (void*)&bias; args[4] = (void*)&x;    args[5] = (void*)&xw;
  args[6] = (void*)&out;  args[7] = (void*)&hbuf; args[8] = (void*)&cb0;
  args[9] = (void*)&cb1;  args[10] = (void*)&thb; args[11] = (void*)&bar;
  args[12] = (void*)&c0;

  hipError_t e = hipLaunchCooperativeKernel((const void*)lstm_loop, dim3(256), dim3(256),
                                            args, (unsigned int)SMEM_B, stream);
  if (e != hipSuccess) {
    // fallback: plain launch (256 blocks == 256 CUs, 1 block/CU by LDS -> co-resident)
    hipLaunchKernelGGL(lstm_loop, dim3(256), dim3(256), SMEM_B, stream,
                       R, P, PRJ, bias, x, xw, out, hbuf, cb0, cb1, thb, bar, c0);
  }
}

// Round 2
// 11989.075 us; speedup vs baseline: 4.6584x; 4.6584x over previous
//
#include <hip/hip_runtime.h>
#include <cstdint>
#include <cstddef>

// Problem dims (fixed): B=64, T=512, D=1024, U=1024
#define NB 64
#define NT 512
#define ND 1024
#define NU 1024

typedef short s16x8 __attribute__((ext_vector_type(8)));   // 8 bf16 (bit pattern)
typedef float f32x4 __attribute__((ext_vector_type(4)));
typedef unsigned short u16;

__device__ __forceinline__ u16 f2bf(float f) {
  unsigned int u = __float_as_uint(f);
  u += 0x7fffu + ((u >> 16) & 1u);           // round-to-nearest-even
  return (u16)(u >> 16);
}
__device__ __forceinline__ float bf2f(u16 s) {
  return __uint_as_float(((unsigned int)s) << 16);
}
__device__ __forceinline__ float hsig(float x) {
  return fminf(fmaxf(0.2f * x + 0.5f, 0.0f), 1.0f);
}
__device__ __forceinline__ f32x4 mfma16(s16x8 a, s16x8 b, f32x4 c) {
  return __builtin_amdgcn_mfma_f32_16x16x32_bf16(a, b, c, 0, 0, 0);
}

// coherent (bypass L1+L2) 2-byte store to the coherent point
__device__ __forceinline__ void stg_cg_u16(u16* p, u16 v) {
  unsigned int vv = v;
  asm volatile("global_store_short %0, %1, off sc0 sc1" :: "v"(p), "v"(vv) : "memory");
}

// wave-local: all my vmem ops acked at coherent point; block compiler motion
#define WAIT_VM0() do { \
    asm volatile("s_waitcnt vmcnt(0)" ::: "memory"); \
    __builtin_amdgcn_sched_barrier(0); \
  } while (0)

// ---------------------------------------------------------------------------
// Kernel 1: xW = x_flat(32768x1024) @ W(1024x4096), bf16 MFMA, out bf16.
// Output layout: XW[((t*64)+b)*4096 + col]
// ---------------------------------------------------------------------------
__global__ __launch_bounds__(256) void xw_gemm(const float* __restrict__ X,
                                               const float* __restrict__ W,
                                               u16* __restrict__ XW) {
  __shared__ u16 Al[128][72];
  __shared__ u16 Bl[128][72];
  const int tid = threadIdx.x;
  const int lane = tid & 63;
  const int wv = tid >> 6;
  const int m0 = (blockIdx.x >> 5) * 128;
  const int n0 = (blockIdx.x & 31) * 128;
  f32x4 acc[4][4];
#pragma unroll
  for (int i = 0; i < 4; ++i)
#pragma unroll
    for (int j = 0; j < 4; ++j) acc[i][j] = (f32x4){0.f, 0.f, 0.f, 0.f};

  for (int kt = 0; kt < 1024; kt += 64) {
    {
      const int r = tid >> 1, hh = (tid & 1) * 32;
      const float* src = X + (size_t)(m0 + r) * 1024 + kt + hh;
      u16* dst = &Al[r][hh];
#pragma unroll
      for (int j = 0; j < 8; ++j) {
        float4 v = ((const float4*)src)[j];
        dst[j * 4 + 0] = f2bf(v.x); dst[j * 4 + 1] = f2bf(v.y);
        dst[j * 4 + 2] = f2bf(v.z); dst[j * 4 + 3] = f2bf(v.w);
      }
    }
    {
      const int kr = tid >> 2, q = (tid & 3) * 32;
      const float* src = W + (size_t)(kt + kr) * 4096 + n0 + q;
#pragma unroll
      for (int j = 0; j < 8; ++j) {
        float4 v = ((const float4*)src)[j];
        const int n = q + j * 4;
        Bl[n + 0][kr] = f2bf(v.x); Bl[n + 1][kr] = f2bf(v.y);
        Bl[n + 2][kr] = f2bf(v.z); Bl[n + 3][kr] = f2bf(v.w);
      }
    }
    __syncthreads();
    const int wm = (wv >> 1) * 64, wn = (wv & 1) * 64;
    const int row = lane & 15, kq = (lane >> 4) * 8;
#pragma unroll
    for (int ks = 0; ks < 2; ++ks) {
      s16x8 af[4], bq[4];
#pragma unroll
      for (int i = 0; i < 4; ++i) af[i] = *(const s16x8*)&Al[wm + i * 16 + row][ks * 32 + kq];
#pragma unroll
      for (int j = 0; j < 4; ++j) bq[j] = *(const s16x8*)&Bl[wn + j * 16 + row][ks * 32 + kq];
#pragma unroll
      for (int i = 0; i < 4; ++i)
#pragma unroll
        for (int j = 0; j < 4; ++j) acc[i][j] = mfma16(af[i], bq[j], acc[i][j]);
    }
    __syncthreads();
  }
  const int wm = (wv >> 1) * 64, wn = (wv & 1) * 64;
  const int col16 = lane & 15, rq = (lane >> 4) * 4;
#pragma unroll
  for (int i = 0; i < 4; ++i)
#pragma unroll
    for (int j = 0; j < 4; ++j)
#pragma unroll
      for (int q = 0; q < 4; ++q) {
        const int m = m0 + wm + i * 16 + rq + q;
        const int n = n0 + wn + j * 16 + col16;
        const int t = m & 511, b = m >> 9;
        XW[((size_t)(t * 64 + b)) * 4096 + n] = f2bf(acc[i][j][q]);
      }
}

// ---------------------------------------------------------------------------
// Kernel 2: init broadcast buffers from h0/c0 (kernel-end flush makes these
// visible to lstm_loop's bypass loads)
// ---------------------------------------------------------------------------
__global__ void init_comm(const float* __restrict__ h0, const float* __restrict__ c0,
                          u16* hbuf, u16* cbuf0) {
  const int i = blockIdx.x * 256 + threadIdx.x;
  hbuf[i] = f2bf(h0[i]);
  cbuf0[i] = f2bf(c0[i]);
}

// ---------------------------------------------------------------------------
// Fence-free grid barrier. Callers must have done WAIT_VM0() after their
// coherent (sc0 sc1) stores. Counter zeroed by hipMemsetAsync per launch.
// ---------------------------------------------------------------------------
__device__ __forceinline__ void gbar(unsigned int* bar, unsigned int target) {
  __syncthreads();
  if (threadIdx.x == 0) {
    __hip_atomic_fetch_add(bar, 1u, __ATOMIC_RELAXED, __HIP_MEMORY_SCOPE_AGENT);
    while (__hip_atomic_load(bar, __ATOMIC_RELAXED, __HIP_MEMORY_SCOPE_AGENT) < target)
      __builtin_amdgcn_s_sleep(1);
  }
  __syncthreads();
}

// ---------------------------------------------------------------------------
// Kernel 3: persistent recurrence. 256 blocks (1/CU) x 256 threads.
// Block owns 8 u-columns x 32 batch rows. Weights resident in LDS (bf16).
// Cell state f32 in registers. All cross-block traffic via sc0/sc1 bypass ops.
// ---------------------------------------------------------------------------
#define WLDS_B   (64 * 1032 * 2)       // 132096
#define ZOFF     WLDS_B
#define POFF     (ZOFF + 32 * 33 * 4)  // 136320
#define OOFF     (POFF + 32 * 17 * 4)  // 138496
#define SMEM_B   (OOFF + 32 * 17 * 4)  // 140672

__global__ __launch_bounds__(256, 1) void lstm_loop(
    const float* __restrict__ rec, const float* __restrict__ peep,
    const float* __restrict__ projw, const float* __restrict__ bias,
    const float* __restrict__ x, const u16* __restrict__ xw,
    float* __restrict__ out,
    u16* hbuf, u16* cbuf0, u16* cbuf1, u16* thbuf,
    unsigned int* bar, const float* __restrict__ c0) {
  extern __shared__ char smem[];
  u16 (*wlds)[1032] = (u16(*)[1032])smem;
  float (*zlds)[33] = (float(*)[33])(smem + ZOFF);
  float (*plds)[17] = (float(*)[17])(smem + POFF);
  float (*olds)[17] = (float(*)[17])(smem + OOFF);

  const int tid = threadIdx.x;
  const int lane = tid & 63;
  const int wv = tid >> 6;
  const int ugrp = blockIdx.x >> 1;
  const int rh = blockIdx.x & 1;
  const int row0 = rh * 32;
  const int u0 = ugrp * 8;

  // ---- stage weight slice into LDS (once), float2-vectorized ----
  // col map: 0-31 R(i,f,c,o), 32-47 Pi|Pf, 48-55 Po, 56-63 proj (all 8 cols of u0..u0+7)
  for (int g = 0; g < 8; ++g) {
    const int c = g * 8 + (tid & 3) * 2;
    const float* sp; int stride, scol;
    if (c < 32)      { sp = rec;   stride = 4096; scol = (c >> 3) * 1024 + u0 + (c & 7); }
    else if (c < 48) { sp = peep;  stride = 3072; scol = ((c - 32) >> 3) * 1024 + u0 + (c & 7); }
    else if (c < 56) { sp = peep;  stride = 3072; scol = 2048 + u0 + (c & 7); }
    else             { sp = projw; stride = 1024; scol = u0 + (c - 56); }
#pragma unroll 4
    for (int p = 0; p < 16; ++p) {
      const int k = p * 64 + (tid >> 2);
      float2 v = *(const float2*)(sp + (size_t)k * stride + scol);
      wlds[c][k] = f2bf(v.x);
      wlds[c + 1][k] = f2bf(v.y);
    }
  }

  const int r = tid >> 3;        // 0..31 local row
  const int ul = tid & 7;        // 0..7 local u
  const int brow = row0 + r;
  const int u = u0 + ul;
  const float b_i = bias[u], b_f = bias[1024 + u], b_c = bias[2048 + u], b_o = bias[3072 + u];
  float cst = c0[brow * 1024 + u];

  __syncthreads();

  unsigned int nbar = 0;
  const int rt = (wv < 2) ? wv : (wv - 2);
  const int fcol = lane & 15;
  const int kofs = (lane >> 4) * 8;

  for (int t = 0; t < NT; ++t) {
    const u16* cprev = (t & 1) ? cbuf1 : cbuf0;
    u16* cnew = (t & 1) ? cbuf0 : cbuf1;
    float zo_reg;

    // early per-thread loads (plain cached; latency hides under A-batch)
    const u16* xr = xw + ((size_t)t * 64 + brow) * 4096;
    const float xw_i = bf2f(xr[u]);
    const float xw_f = bf2f(xr[1024 + u]);
    const float xw_c = bf2f(xr[2048 + u]);
    const float xw_o = bf2f(xr[3072 + u]);
    const size_t xo = (size_t)brow * (512 * 1024) + (size_t)t * 1024 + u;
    const float xres = x[xo];

    // ===== phase 1: z = h@R (+xW+bias), peephole c@Pi/Pf, c_new =====
    {
      const int arow = row0 + rt * 16 + fcol;
      const u16* ap = ((wv < 2) ? (const u16*)hbuf : cprev) + arow * 1024 + kofs;
      s16x8 av[32];
#pragma unroll
      for (int kt = 0; kt < 32; ++kt)
        asm volatile("global_load_dwordx4 %0, %1, off sc0 sc1"
                     : "=v"(av[kt]) : "v"(ap + kt * 32));
      WAIT_VM0();
      f32x4 accA = {0.f, 0.f, 0.f, 0.f}, accB = {0.f, 0.f, 0.f, 0.f};
      if (wv < 2) {
        const u16* bp0 = &wlds[fcol][kofs];
        const u16* bp1 = &wlds[16 + fcol][kofs];
#pragma unroll
        for (int kt = 0; kt < 32; ++kt) {
          accA = mfma16(av[kt], *(const s16x8*)(bp0 + kt * 32), accA);
          accB = mfma16(av[kt], *(const s16x8*)(bp1 + kt * 32), accB);
        }
      } else {
        const u16* bp = &wlds[32 + fcol][kofs];
#pragma unroll
        for (int kt = 0; kt < 32; ++kt)
          accA = mfma16(av[kt], *(const s16x8*)(bp + kt * 32), accA);
      }
      const int srow = rt * 16 + (lane >> 4) * 4;
      if (wv < 2) {
#pragma unroll
        for (int q = 0; q < 4; ++q) {
          zlds[srow + q][fcol] = accA[q];
          zlds[srow + q][16 + fcol] = accB[q];
        }
      } else {
#pragma unroll
        for (int q = 0; q < 4; ++q) plds[srow + q][fcol] = accA[q];
      }
    }
    __syncthreads();
    {
      const float zi = zlds[r][ul]      + xw_i + b_i + plds[r][ul];
      const float zf = zlds[r][8 + ul]  + xw_f + b_f + plds[r][8 + ul];
      const float zc = zlds[r][16 + ul] + xw_c + b_c;
      zo_reg         = zlds[r][24 + ul] + xw_o + b_o;
      const float ig = hsig(zi), fg = hsig(zf);
      cst = fg * cst + ig * tanhf(zc);
      const float th = tanhf(cst);
      stg_cg_u16(cnew + brow * 1024 + u, f2bf(cst));
      stg_cg_u16(thbuf + brow * 1024 + u, f2bf(th));
    }
    WAIT_VM0();
    ++nbar; gbar(bar, nbar * 256u);   // c_new / tanh(c_new) published

    // ===== phase 2: o = hsig(zo + c_new@Po); h = o*(tanh(c_new)@proj + x_t) =====
    {
      const int prt = wv & 1;
      const int arow = row0 + prt * 16 + fcol;
      const u16* ap = ((wv < 2) ? (const u16*)cnew : (const u16*)thbuf) + arow * 1024 + kofs;
      s16x8 av[32];
#pragma unroll
      for (int kt = 0; kt < 32; ++kt)
        asm volatile("global_load_dwordx4 %0, %1, off sc0 sc1"
                     : "=v"(av[kt]) : "v"(ap + kt * 32));
      WAIT_VM0();
      f32x4 acc = {0.f, 0.f, 0.f, 0.f};
      const u16* bp = &wlds[48 + fcol][kofs];   // cols 0-7 Po, 8-15 proj
#pragma unroll
      for (int kt = 0; kt < 32; ++kt)
        acc = mfma16(av[kt], *(const s16x8*)(bp + kt * 32), acc);
      const int srow = prt * 16 + (lane >> 4) * 4;
      if (wv < 2) {
        if (fcol < 8) {
#pragma unroll
          for (int q = 0; q < 4; ++q) olds[srow + q][fcol] = acc[q];
        }
      } else {
        if (fcol >= 8) {
#pragma unroll
          for (int q = 0; q < 4; ++q) olds[srow + q][fcol] = acc[q];
        }
      }
    }
    __syncthreads();
    {
      const float og = hsig(zo_reg + olds[r][ul]);
      const float pv = olds[r][8 + ul] + xres;
      const float hv = og * pv;
      out[xo] = hv;                              // plain store (host reads after kernel)
      stg_cg_u16(hbuf + brow * 1024 + u, f2bf(hv));
    }
    WAIT_VM0();
    ++nbar; gbar(bar, nbar * 256u);   // h published
  }
}

// ---------------------------------------------------------------------------
// Host launcher
// ---------------------------------------------------------------------------
extern "C" void kernel_launch(void* const* d_in, const int* in_sizes, int n_in,
                              void* d_out, int out_size, void* d_ws, size_t ws_size,
                              hipStream_t stream) {
  const float* x    = (const float*)d_in[0];
  const float* h0   = (const float*)d_in[1];
  const float* c0   = (const float*)d_in[2];
  const float* W    = (const float*)d_in[3];
  const float* R    = (const float*)d_in[4];
  const float* P    = (const float*)d_in[5];
  const float* PRJ  = (const float*)d_in[6];
  const float* bias = (const float*)d_in[7];
  float* out = (float*)d_out;
  char* ws = (char*)d_ws;

  const size_t XW_BYTES = (size_t)32768 * 4096 * 2;   // 268435456
  size_t off = XW_BYTES;
  u16* xw   = (u16*)ws;
  u16* hbuf = (u16*)(ws + off); off += 131072;
  u16* cb0  = (u16*)(ws + off); off += 131072;
  u16* cb1  = (u16*)(ws + off); off += 131072;
  u16* thb  = (u16*)(ws + off); off += 131072;
  unsigned int* bar = (unsigned int*)(ws + off); off += 4096;
  if (ws_size < off) return;

  (void)hipFuncSetAttribute(reinterpret_cast<const void*>(&lstm_loop),
                            hipFuncAttributeMaxDynamicSharedMemorySize, 160 * 1024);

  hipMemsetAsync(bar, 0, 4096, stream);
  hipLaunchKernelGGL(init_comm, dim3(256), dim3(256), 0, stream, h0, c0, hbuf, cb0);
  hipLaunchKernelGGL(xw_gemm, dim3(8192), dim3(256), 0, stream, x, W, xw);

  void* args[13];
  args[0] = (void*)&R;    args[1] = (void*)&P;    args[2] = (void*)&PRJ;
  args[3] = (void*)&bias; args[4] = (void*)&x;    args[5] = (void*)&xw;
  args[6] = (void*)&out;  args[7] = (void*)&hbuf; args[8] = (void*)&cb0;
  args[9] = (void*)&cb1;  args[10] = (void*)&thb; args[11] = (void*)&bar;
  args[12] = (void*)&c0;

  hipError_t e = hipLaunchCooperativeKernel((const void*)lstm_loop, dim3(256), dim3(256),
                                            args, (unsigned int)SMEM_B, stream);
  if (e != hipSuccess) {
    hipLaunchKernelGGL(lstm_loop, dim3(256), dim3(256), SMEM_B, stream,
                       R, P, PRJ, bias, x, xw, out, hbuf, cb0, cb1, thb, bar, c0);
  }
}

// Round 4
// 8018.344 us; speedup vs baseline: 6.9653x; 1.4952x over previous
//
#include <hip/hip_runtime.h>
#include <cstdint>
#include <cstddef>

// Problem dims (fixed): B=64, T=512, D=1024, U=1024
#define NB 64
#define NT 512
#define ND 1024
#define NU 1024

typedef short s16x8 __attribute__((ext_vector_type(8)));   // 8 bf16 (bit pattern)
typedef float f32x4 __attribute__((ext_vector_type(4)));
typedef unsigned short u16;

__device__ __forceinline__ u16 f2bf(float f) {
  unsigned int u = __float_as_uint(f);
  u += 0x7fffu + ((u >> 16) & 1u);           // round-to-nearest-even
  return (u16)(u >> 16);
}
__device__ __forceinline__ float bf2f(u16 s) {
  return __uint_as_float(((unsigned int)s) << 16);
}
__device__ __forceinline__ float hsig(float x) {
  return fminf(fmaxf(0.2f * x + 0.5f, 0.0f), 1.0f);
}
__device__ __forceinline__ f32x4 mfma16(s16x8 a, s16x8 b, f32x4 c) {
  return __builtin_amdgcn_mfma_f32_16x16x32_bf16(a, b, c, 0, 0, 0);
}

// no-return far atomic u32 swap: executes AT the coherent point (L3); its
// vmcnt ack == globally visible. This is the store primitive for ALL
// cross-block communicated data (c, th, h, barrier flags).
__device__ __forceinline__ void atomic_swap_u32(unsigned int* p, unsigned int v) {
  asm volatile("global_atomic_swap %0, %1, off" :: "v"(p), "v"(v) : "memory");
}

// wave-local: all my vmem ops (incl. atomics) executed; block compiler motion
#define WAIT_VM0() do { \
    asm volatile("s_waitcnt vmcnt(0)" ::: "memory"); \
    __builtin_amdgcn_sched_barrier(0); \
  } while (0)

// ---------------------------------------------------------------------------
// Kernel 1: xW = x_flat(32768x1024) @ W(1024x4096), bf16 MFMA, out bf16.
// Output layout: XW[ugrp][t][b][g*8+ul]  (one fully-used 64B line per (block,row))
// ---------------------------------------------------------------------------
__global__ __launch_bounds__(256) void xw_gemm(const float* __restrict__ X,
                                               const float* __restrict__ W,
                                               u16* __restrict__ XW) {
  __shared__ u16 Al[128][72];
  __shared__ u16 Bl[128][72];
  const int tid = threadIdx.x;
  const int lane = tid & 63;
  const int wv = tid >> 6;
  const int m0 = (blockIdx.x >> 5) * 128;
  const int n0 = (blockIdx.x & 31) * 128;
  f32x4 acc[4][4];
#pragma unroll
  for (int i = 0; i < 4; ++i)
#pragma unroll
    for (int j = 0; j < 4; ++j) acc[i][j] = (f32x4){0.f, 0.f, 0.f, 0.f};

  for (int kt = 0; kt < 1024; kt += 64) {
    {
      const int r = tid >> 1, hh = (tid & 1) * 32;
      const float* src = X + (size_t)(m0 + r) * 1024 + kt + hh;
      u16* dst = &Al[r][hh];
#pragma unroll
      for (int j = 0; j < 8; ++j) {
        float4 v = ((const float4*)src)[j];
        dst[j * 4 + 0] = f2bf(v.x); dst[j * 4 + 1] = f2bf(v.y);
        dst[j * 4 + 2] = f2bf(v.z); dst[j * 4 + 3] = f2bf(v.w);
      }
    }
    {
      const int kr = tid >> 2, q = (tid & 3) * 32;
      const float* src = W + (size_t)(kt + kr) * 4096 + n0 + q;
#pragma unroll
      for (int j = 0; j < 8; ++j) {
        float4 v = ((const float4*)src)[j];
        const int n = q + j * 4;
        Bl[n + 0][kr] = f2bf(v.x); Bl[n + 1][kr] = f2bf(v.y);
        Bl[n + 2][kr] = f2bf(v.z); Bl[n + 3][kr] = f2bf(v.w);
      }
    }
    __syncthreads();
    const int wm = (wv >> 1) * 64, wn = (wv & 1) * 64;
    const int row = lane & 15, kq = (lane >> 4) * 8;
#pragma unroll
    for (int ks = 0; ks < 2; ++ks) {
      s16x8 af[4], bq[4];
#pragma unroll
      for (int i = 0; i < 4; ++i) af[i] = *(const s16x8*)&Al[wm + i * 16 + row][ks * 32 + kq];
#pragma unroll
      for (int j = 0; j < 4; ++j) bq[j] = *(const s16x8*)&Bl[wn + j * 16 + row][ks * 32 + kq];
#pragma unroll
      for (int i = 0; i < 4; ++i)
#pragma unroll
        for (int j = 0; j < 4; ++j) acc[i][j] = mfma16(af[i], bq[j], acc[i][j]);
    }
    __syncthreads();
  }
  const int wm = (wv >> 1) * 64, wn = (wv & 1) * 64;
  const int col16 = lane & 15, rq = (lane >> 4) * 4;
#pragma unroll
  for (int i = 0; i < 4; ++i)
#pragma unroll
    for (int j = 0; j < 4; ++j)
#pragma unroll
      for (int q = 0; q < 4; ++q) {
        const int m = m0 + wm + i * 16 + rq + q;
        const int n = n0 + wn + j * 16 + col16;   // 0..4095 = g*1024 + u
        const int t = m & 511, b = m >> 9;
        const int g = n >> 10, uu = n & 1023;
        const int ugrp = uu >> 3, ul2 = uu & 7;
        XW[(((size_t)ugrp * 512 + t) * 64 + b) * 32 + g * 8 + ul2] = f2bf(acc[i][j][q]);
      }
}

// ---------------------------------------------------------------------------
// Kernel 2: init broadcast buffers from h0/c0
// ---------------------------------------------------------------------------
__global__ void init_comm(const float* __restrict__ h0, const float* __restrict__ c0,
                          u16* hbuf, u16* cbuf) {
  const int i = blockIdx.x * 256 + threadIdx.x;
  hbuf[i] = f2bf(h0[i]);
  cbuf[i] = f2bf(c0[i]);
}

// ---------------------------------------------------------------------------
// All-to-all flag barrier. Each block's t0 atomically swaps its epoch into
// flags[bid*16] (far atomic => visible when acked); thread tid polls
// flags[tid*16] with a bypass load. Callers must WAIT_VM0() their data
// atomics first. Flags zeroed per launch (in-graph memset).
// ---------------------------------------------------------------------------
__device__ __forceinline__ void gbar(unsigned int* flags, int bid, int tid, unsigned int ep) {
  __syncthreads();                       // all waves' data atomics acked
  if (tid == 0) atomic_swap_u32(flags + bid * 16, ep);
  unsigned int* f = flags + tid * 16;
  for (;;) {
    unsigned int v;
    asm volatile("global_load_dword %0, %1, off sc0 sc1\n\ts_waitcnt vmcnt(0)"
                 : "=v"(v) : "v"(f) : "memory");
    if (v >= ep) break;
    __builtin_amdgcn_s_sleep(1);
  }
  __syncthreads();
}

// ---------------------------------------------------------------------------
// Kernel 3: persistent recurrence. 256 blocks (1/CU) x 256 threads.
// Block owns 8 u-columns x 32 batch rows. Weights resident in LDS (bf16).
// Cell state f32 in registers. Waves 0-1 keep c-fragments in registers across
// barrier B (loaded in phase 2, reused for next step's peephole).
// All cross-block data published via far-atomic u32 swaps (pair-packed bf16).
// ---------------------------------------------------------------------------
#define WLDS_B   (64 * 1032 * 2)       // 132096
#define ZOFF     WLDS_B
#define POFF     (ZOFF + 32 * 33 * 4)  // 136320
#define OOFF     (POFF + 32 * 17 * 4)  // 138496
#define SMEM_B   (OOFF + 32 * 17 * 4)  // 140672

__global__ __launch_bounds__(256, 1) void lstm_loop(
    const float* __restrict__ rec, const float* __restrict__ peep,
    const float* __restrict__ projw, const float* __restrict__ bias,
    const float* __restrict__ x, const u16* __restrict__ xw,
    float* __restrict__ out,
    u16* hbuf, u16* cbuf, u16* thbuf,
    unsigned int* flags, const float* __restrict__ c0) {
  extern __shared__ char smem[];
  u16 (*wlds)[1032] = (u16(*)[1032])smem;
  float (*zlds)[33] = (float(*)[33])(smem + ZOFF);
  float (*plds)[17] = (float(*)[17])(smem + POFF);
  float (*olds)[17] = (float(*)[17])(smem + OOFF);

  const int tid = threadIdx.x;
  const int lane = tid & 63;
  const int wv = tid >> 6;
  const int bid = blockIdx.x;
  const int ugrp = bid >> 1;
  const int row0 = (bid & 1) * 32;
  const int u0 = ugrp * 8;

  // ---- stage weight slice into LDS (once), float2-vectorized ----
  // col map: 0-31 R(i,f,c,o), 32-47 Pi|Pf, 48-55 Po, 56-63 proj
  for (int g = 0; g < 8; ++g) {
    const int c = g * 8 + (tid & 3) * 2;
    const float* sp; int stride, scol;
    if (c < 32)      { sp = rec;   stride = 4096; scol = (c >> 3) * 1024 + u0 + (c & 7); }
    else if (c < 48) { sp = peep;  stride = 3072; scol = ((c - 32) >> 3) * 1024 + u0 + (c & 7); }
    else if (c < 56) { sp = peep;  stride = 3072; scol = 2048 + u0 + (c & 7); }
    else             { sp = projw; stride = 1024; scol = u0 + (c - 56); }
#pragma unroll 4
    for (int p = 0; p < 16; ++p) {
      const int k = p * 64 + (tid >> 2);
      float2 v = *(const float2*)(sp + (size_t)k * stride + scol);
      wlds[c][k] = f2bf(v.x);
      wlds[c + 1][k] = f2bf(v.y);
    }
  }

  const int r = tid >> 3;        // 0..31 local row
  const int ul = tid & 7;        // 0..7 local u
  const int brow = row0 + r;
  const int u = u0 + ul;
  const float b_i = bias[u], b_f = bias[1024 + u], b_c = bias[2048 + u], b_o = bias[3072 + u];
  float cst = c0[brow * 1024 + u];

  const int fcol = lane & 15;
  const int kofs = (lane >> 4) * 8;

  s16x8 av[32];    // waves 0-1: c fragments (persist across barrier B); waves 2-3: scratch
  if (wv < 2) {    // preload c0 fragments (rows row0 + wv*16 + fcol)
    const u16* ap = cbuf + (size_t)(row0 + wv * 16 + fcol) * 1024 + kofs;
#pragma unroll
    for (int kt = 0; kt < 32; ++kt)
      asm volatile("global_load_dwordx4 %0, %1, off sc0 sc1"
                   : "=v"(av[kt]) : "v"(ap + kt * 32));
  }
  WAIT_VM0();
  __syncthreads();

  for (int t = 0; t < NT; ++t) {
    float zo_reg;

    // early per-thread cached loads (latency hides under phase-1 batch)
    const u16* xr = xw + (((size_t)ugrp * 512 + t) * 64 + brow) * 32;
    const float xw_i = bf2f(xr[ul]);
    const float xw_f = bf2f(xr[8 + ul]);
    const float xw_c = bf2f(xr[16 + ul]);
    const float xw_o = bf2f(xr[24 + ul]);
    const size_t xo = (size_t)brow * (512 * 1024) + (size_t)t * 1024 + u;
    const float xres = x[xo];

    // ===== phase 1: waves 2-3 load h + compute z=h@R; waves 0-1 peephole from regs =====
    if (wv >= 2) {
      const int rt = wv - 2;
      const u16* ap = hbuf + (size_t)(row0 + rt * 16 + fcol) * 1024 + kofs;
#pragma unroll
      for (int kt = 0; kt < 32; ++kt)
        asm volatile("global_load_dwordx4 %0, %1, off sc0 sc1"
                     : "=v"(av[kt]) : "v"(ap + kt * 32));
      WAIT_VM0();
      f32x4 accA = {0.f, 0.f, 0.f, 0.f}, accB = {0.f, 0.f, 0.f, 0.f};
      const u16* bp0 = &wlds[fcol][kofs];
      const u16* bp1 = &wlds[16 + fcol][kofs];
#pragma unroll
      for (int kt = 0; kt < 32; ++kt) {
        accA = mfma16(av[kt], *(const s16x8*)(bp0 + kt * 32), accA);
        accB = mfma16(av[kt], *(const s16x8*)(bp1 + kt * 32), accB);
      }
      const int srow = rt * 16 + (lane >> 4) * 4;
#pragma unroll
      for (int q = 0; q < 4; ++q) {
        zlds[srow + q][fcol] = accA[q];
        zlds[srow + q][16 + fcol] = accB[q];
      }
    } else {
      f32x4 accP = {0.f, 0.f, 0.f, 0.f};
      const u16* bp = &wlds[32 + fcol][kofs];
#pragma unroll
      for (int kt = 0; kt < 32; ++kt)
        accP = mfma16(av[kt], *(const s16x8*)(bp + kt * 32), accP);
      const int srow = wv * 16 + (lane >> 4) * 4;
#pragma unroll
      for (int q = 0; q < 4; ++q) plds[srow + q][fcol] = accP[q];
    }
    __syncthreads();
    {
      const float zi = zlds[r][ul]      + xw_i + b_i + plds[r][ul];
      const float zf = zlds[r][8 + ul]  + xw_f + b_f + plds[r][8 + ul];
      const float zc = zlds[r][16 + ul] + xw_c + b_c;
      zo_reg         = zlds[r][24 + ul] + xw_o + b_o;
      const float ig = hsig(zi), fg = hsig(zf);
      cst = fg * cst + ig * tanhf(zc);
      const float th = tanhf(cst);
      // pair-pack (u even|u odd) via shfl, publish with far-atomic swaps
      const unsigned int cb = f2bf(cst), tb = f2bf(th);
      const unsigned int cpart = (unsigned int)__shfl_xor((int)cb, 1);
      const unsigned int tpart = (unsigned int)__shfl_xor((int)tb, 1);
      if ((ul & 1) == 0) {
        atomic_swap_u32((unsigned int*)(cbuf + brow * 1024 + u), (cpart << 16) | cb);
        atomic_swap_u32((unsigned int*)(thbuf + brow * 1024 + u), (tpart << 16) | tb);
      }
    }
    WAIT_VM0();
    gbar(flags, bid, tid, 2 * t + 1);   // c_new / tanh(c_new) published (at L3)

    // ===== phase 2: o = hsig(zo + c_new@Po); h = o*(tanh(c_new)@proj + x_t) =====
    {
      const int prt = wv & 1;
      const u16* ap = ((wv < 2) ? (const u16*)cbuf : (const u16*)thbuf)
                      + (size_t)(row0 + prt * 16 + fcol) * 1024 + kofs;
#pragma unroll
      for (int kt = 0; kt < 32; ++kt)
        asm volatile("global_load_dwordx4 %0, %1, off sc0 sc1"
                     : "=v"(av[kt]) : "v"(ap + kt * 32));
      WAIT_VM0();
      f32x4 acc = {0.f, 0.f, 0.f, 0.f};
      const u16* bp = &wlds[48 + fcol][kofs];   // cols 0-7 Po, 8-15 proj
#pragma unroll
      for (int kt = 0; kt < 32; ++kt)
        acc = mfma16(av[kt], *(const s16x8*)(bp + kt * 32), acc);
      const int srow = prt * 16 + (lane >> 4) * 4;
      if (wv < 2) {        // A = c_new -> Po result valid on cols 0-7
        if (fcol < 8) {
#pragma unroll
          for (int q = 0; q < 4; ++q) olds[srow + q][fcol] = acc[q];
        }
      } else {             // A = tanh(c_new) -> proj result valid on cols 8-15
        if (fcol >= 8) {
#pragma unroll
          for (int q = 0; q < 4; ++q) olds[srow + q][fcol] = acc[q];
        }
      }
    }
    __syncthreads();
    {
      const float og = hsig(zo_reg + olds[r][ul]);
      const float pv = olds[r][8 + ul] + xres;
      const float hv = og * pv;
      out[xo] = hv;
      const unsigned int hb = f2bf(hv);
      const unsigned int hpart = (unsigned int)__shfl_xor((int)hb, 1);
      if ((ul & 1) == 0)
        atomic_swap_u32((unsigned int*)(hbuf + brow * 1024 + u), (hpart << 16) | hb);
    }
    WAIT_VM0();
    gbar(flags, bid, tid, 2 * t + 2);   // h published (at L3)
  }
}

// ---------------------------------------------------------------------------
// Host launcher
// ---------------------------------------------------------------------------
extern "C" void kernel_launch(void* const* d_in, const int* in_sizes, int n_in,
                              void* d_out, int out_size, void* d_ws, size_t ws_size,
                              hipStream_t stream) {
  const float* x    = (const float*)d_in[0];
  const float* h0   = (const float*)d_in[1];
  const float* c0   = (const float*)d_in[2];
  const float* W    = (const float*)d_in[3];
  const float* R    = (const float*)d_in[4];
  const float* P    = (const float*)d_in[5];
  const float* PRJ  = (const float*)d_in[6];
  const float* bias = (const float*)d_in[7];
  float* out = (float*)d_out;
  char* ws = (char*)d_ws;

  const size_t XW_BYTES = (size_t)32768 * 4096 * 2;   // 268435456
  size_t off = XW_BYTES;
  u16* xw   = (u16*)ws;
  u16* hbuf = (u16*)(ws + off); off += 131072;
  u16* cbuf = (u16*)(ws + off); off += 131072;
  u16* thb  = (u16*)(ws + off); off += 131072;
  unsigned int* flags = (unsigned int*)(ws + off); off += 16384;
  if (ws_size < off) return;

  (void)hipFuncSetAttribute(reinterpret_cast<const void*>(&lstm_loop),
                            hipFuncAttributeMaxDynamicSharedMemorySize, 160 * 1024);

  hipMemsetAsync(flags, 0, 16384, stream);
  hipLaunchKernelGGL(init_comm, dim3(256), dim3(256), 0, stream, h0, c0, hbuf, cbuf);
  hipLaunchKernelGGL(xw_gemm, dim3(8192), dim3(256), 0, stream, x, W, xw);

  void* args[12];
  args[0] = (void*)&R;    args[1] = (void*)&P;     args[2] = (void*)&PRJ;
  args[3] = (void*)&bias; args[4] = (void*)&x;     args[5] = (void*)&xw;
  args[6] = (void*)&out;  args[7] = (void*)&hbuf;  args[8] = (void*)&cbuf;
  args[9] = (void*)&thb;  args[10] = (void*)&flags; args[11] = (void*)&c0;

  hipError_t e = hipLaunchCooperativeKernel((const void*)lstm_loop, dim3(256), dim3(256),
                                            args, (unsigned int)SMEM_B, stream);
  if (e != hipSuccess) {
    hipLaunchKernelGGL(lstm_loop, dim3(256), dim3(256), SMEM_B, stream,
                       R, P, PRJ, bias, x, xw, out, hbuf, cbuf, thb, flags, c0);
  }
}

// Round 5
// 7836.243 us; speedup vs baseline: 7.1271x; 1.0232x over previous
//
#include <hip/hip_runtime.h>
#include <cstdint>
#include <cstddef>

// Problem dims (fixed): B=64, T=512, D=1024, U=1024
#define NB 64
#define NT 512
#define ND 1024
#define NU 1024

typedef short s16x8 __attribute__((ext_vector_type(8)));   // 8 bf16 (bit pattern)
typedef float f32x4 __attribute__((ext_vector_type(4)));
typedef unsigned int u32x2 __attribute__((ext_vector_type(2)));
typedef unsigned short u16;

__device__ __forceinline__ u16 f2bf(float f) {
  unsigned int u = __float_as_uint(f);
  u += 0x7fffu + ((u >> 16) & 1u);           // round-to-nearest-even
  return (u16)(u >> 16);
}
__device__ __forceinline__ float bf2f(u16 s) {
  return __uint_as_float(((unsigned int)s) << 16);
}
__device__ __forceinline__ float hsig(float x) {
  return fminf(fmaxf(0.2f * x + 0.5f, 0.0f), 1.0f);
}
__device__ __forceinline__ f32x4 mfma16(s16x8 a, s16x8 b, f32x4 c) {
  return __builtin_amdgcn_mfma_f32_16x16x32_bf16(a, b, c, 0, 0, 0);
}

// no-return far atomic u32 swap: executes AT the coherent point (L3); its
// vmcnt ack == globally visible. Store primitive for ALL cross-block data.
__device__ __forceinline__ void atomic_swap_u32(unsigned int* p, unsigned int v) {
  asm volatile("global_atomic_swap %0, %1, off" :: "v"(p), "v"(v) : "memory");
}

// wave-local: all my vmem ops (incl. atomics) executed; block compiler motion
#define WAIT_VM0() do { \
    asm volatile("s_waitcnt vmcnt(0)" ::: "memory"); \
    __builtin_amdgcn_sched_barrier(0); \
  } while (0)

// ---------------------------------------------------------------------------
// Kernel 1: xW = x_flat(32768x1024) @ W(1024x4096), bf16 MFMA, out bf16.
// Output layout: XW[ugrp][t][b][ul*4 + gate]  (per-(row,u) gates contiguous ->
// one dwordx2 prefetch per thread in the loop kernel)
// ---------------------------------------------------------------------------
__global__ __launch_bounds__(256) void xw_gemm(const float* __restrict__ X,
                                               const float* __restrict__ W,
                                               u16* __restrict__ XW) {
  __shared__ u16 Al[128][72];
  __shared__ u16 Bl[128][72];
  const int tid = threadIdx.x;
  const int lane = tid & 63;
  const int wv = tid >> 6;
  const int m0 = (blockIdx.x >> 5) * 128;
  const int n0 = (blockIdx.x & 31) * 128;
  f32x4 acc[4][4];
#pragma unroll
  for (int i = 0; i < 4; ++i)
#pragma unroll
    for (int j = 0; j < 4; ++j) acc[i][j] = (f32x4){0.f, 0.f, 0.f, 0.f};

  for (int kt = 0; kt < 1024; kt += 64) {
    {
      const int r = tid >> 1, hh = (tid & 1) * 32;
      const float* src = X + (size_t)(m0 + r) * 1024 + kt + hh;
      u16* dst = &Al[r][hh];
#pragma unroll
      for (int j = 0; j < 8; ++j) {
        float4 v = ((const float4*)src)[j];
        dst[j * 4 + 0] = f2bf(v.x); dst[j * 4 + 1] = f2bf(v.y);
        dst[j * 4 + 2] = f2bf(v.z); dst[j * 4 + 3] = f2bf(v.w);
      }
    }
    {
      const int kr = tid >> 2, q = (tid & 3) * 32;
      const float* src = W + (size_t)(kt + kr) * 4096 + n0 + q;
#pragma unroll
      for (int j = 0; j < 8; ++j) {
        float4 v = ((const float4*)src)[j];
        const int n = q + j * 4;
        Bl[n + 0][kr] = f2bf(v.x); Bl[n + 1][kr] = f2bf(v.y);
        Bl[n + 2][kr] = f2bf(v.z); Bl[n + 3][kr] = f2bf(v.w);
      }
    }
    __syncthreads();
    const int wm = (wv >> 1) * 64, wn = (wv & 1) * 64;
    const int row = lane & 15, kq = (lane >> 4) * 8;
#pragma unroll
    for (int ks = 0; ks < 2; ++ks) {
      s16x8 af[4], bq[4];
#pragma unroll
      for (int i = 0; i < 4; ++i) af[i] = *(const s16x8*)&Al[wm + i * 16 + row][ks * 32 + kq];
#pragma unroll
      for (int j = 0; j < 4; ++j) bq[j] = *(const s16x8*)&Bl[wn + j * 16 + row][ks * 32 + kq];
#pragma unroll
      for (int i = 0; i < 4; ++i)
#pragma unroll
        for (int j = 0; j < 4; ++j) acc[i][j] = mfma16(af[i], bq[j], acc[i][j]);
    }
    __syncthreads();
  }
  const int wm = (wv >> 1) * 64, wn = (wv & 1) * 64;
  const int col16 = lane & 15, rq = (lane >> 4) * 4;
#pragma unroll
  for (int i = 0; i < 4; ++i)
#pragma unroll
    for (int j = 0; j < 4; ++j)
#pragma unroll
      for (int q = 0; q < 4; ++q) {
        const int m = m0 + wm + i * 16 + rq + q;
        const int n = n0 + wn + j * 16 + col16;   // 0..4095 = g*1024 + u
        const int t = m & 511, b = m >> 9;
        const int g = n >> 10, uu = n & 1023;
        const int ugrp = uu >> 3, ul2 = uu & 7;
        XW[(((size_t)ugrp * 512 + t) * 64 + b) * 32 + ul2 * 4 + g] = f2bf(acc[i][j][q]);
      }
}

// ---------------------------------------------------------------------------
// Kernel 2: init broadcast buffers from h0/c0
// ---------------------------------------------------------------------------
__global__ void init_comm(const float* __restrict__ h0, const float* __restrict__ c0,
                          u16* hbuf, u16* cbuf) {
  const int i = blockIdx.x * 256 + threadIdx.x;
  hbuf[i] = f2bf(h0[i]);
  cbuf[i] = f2bf(c0[i]);
}

// ---------------------------------------------------------------------------
// All-to-all flag barrier over the block's OWN row-group (128 blocks; the two
// batch-row halves are fully independent). t0 far-atomically swaps its epoch
// into flags[bid*16]; thread tid polls the flag of group-block (tid&127).
// Callers must WAIT_VM0() their data atomics first. Flags zeroed per launch.
// ---------------------------------------------------------------------------
__device__ __forceinline__ void gbar(unsigned int* flags, int bid, int tid, unsigned int ep) {
  __syncthreads();                       // all waves' data atomics acked
  if (tid == 0) atomic_swap_u32(flags + bid * 16, ep);
  unsigned int* f = flags + ((((tid & 127) << 1) | (bid & 1)) * 16);
  for (;;) {
    unsigned int v;
    asm volatile("global_load_dword %0, %1, off sc0 sc1\n\ts_waitcnt vmcnt(0)"
                 : "=v"(v) : "v"(f) : "memory");
    if (v >= ep) break;
    __builtin_amdgcn_s_sleep(1);
  }
  __syncthreads();
}

// ---------------------------------------------------------------------------
// Kernel 3: persistent recurrence. 256 blocks (1/CU) x 256 threads.
// Block owns 8 u-columns x 32 batch rows. Weights resident in LDS (bf16).
// Cell state f32 in registers. Waves 0-1 keep c-fragments in registers across
// barrier B (loaded in phase 2, reused for next step's peephole).
// xw/x are software-pipelined one step ahead (issued in phase 2, counted
// vmcnt so they never sit in a critical wait). out store issued post-barrier.
// ---------------------------------------------------------------------------
#define WLDS_B   (64 * 1032 * 2)       // 132096
#define ZOFF     WLDS_B
#define POFF     (ZOFF + 32 * 33 * 4)  // 136320
#define OOFF     (POFF + 32 * 17 * 4)  // 138496
#define SMEM_B   (OOFF + 32 * 17 * 4)  // 140672

__global__ __launch_bounds__(256, 1) void lstm_loop(
    const float* __restrict__ rec, const float* __restrict__ peep,
    const float* __restrict__ projw, const float* __restrict__ bias,
    const float* __restrict__ x, const u16* __restrict__ xw,
    float* __restrict__ out,
    u16* hbuf, u16* cbuf, u16* thbuf,
    unsigned int* flags, const float* __restrict__ c0) {
  extern __shared__ char smem[];
  u16 (*wlds)[1032] = (u16(*)[1032])smem;
  float (*zlds)[33] = (float(*)[33])(smem + ZOFF);
  float (*plds)[17] = (float(*)[17])(smem + POFF);
  float (*olds)[17] = (float(*)[17])(smem + OOFF);

  const int tid = threadIdx.x;
  const int lane = tid & 63;
  const int wv = tid >> 6;
  const int bid = blockIdx.x;
  const int ugrp = bid >> 1;
  const int row0 = (bid & 1) * 32;
  const int u0 = ugrp * 8;

  // ---- stage weight slice into LDS (once), float2-vectorized ----
  // col map: 0-31 R(i,f,c,o), 32-47 Pi|Pf, 48-55 Po, 56-63 proj
  for (int g = 0; g < 8; ++g) {
    const int c = g * 8 + (tid & 3) * 2;
    const float* sp; int stride, scol;
    if (c < 32)      { sp = rec;   stride = 4096; scol = (c >> 3) * 1024 + u0 + (c & 7); }
    else if (c < 48) { sp = peep;  stride = 3072; scol = ((c - 32) >> 3) * 1024 + u0 + (c & 7); }
    else if (c < 56) { sp = peep;  stride = 3072; scol = 2048 + u0 + (c & 7); }
    else             { sp = projw; stride = 1024; scol = u0 + (c - 56); }
#pragma unroll 4
    for (int p = 0; p < 16; ++p) {
      const int k = p * 64 + (tid >> 2);
      float2 v = *(const float2*)(sp + (size_t)k * stride + scol);
      wlds[c][k] = f2bf(v.x);
      wlds[c + 1][k] = f2bf(v.y);
    }
  }

  const int r = tid >> 3;        // 0..31 local row
  const int ul = tid & 7;        // 0..7 local u
  const int brow = row0 + r;
  const int u = u0 + ul;
  const float b_i = bias[u], b_f = bias[1024 + u], b_c = bias[2048 + u], b_o = bias[3072 + u];
  float cst = c0[brow * 1024 + u];

  const int fcol = lane & 15;
  const int kofs = (lane >> 4) * 8;

  s16x8 av[32];    // waves 0-1: c fragments (persist across barrier B); waves 2-3: scratch
  u32x2 xwp;       // prefetched xw gates (i|f , c|o) for step t
  float xp;        // prefetched x residual for step t

  // ---- prologue: prefetch t=0 streams + preload c0 fragments ----
  {
    const u16* xr0 = xw + (((size_t)ugrp * 512 + 0) * 64 + brow) * 32 + ul * 4;
    asm volatile("global_load_dwordx2 %0, %1, off" : "=v"(xwp) : "v"(xr0));
    const float* xs0 = x + (size_t)brow * (512 * 1024) + u;
    asm volatile("global_load_dword %0, %1, off" : "=v"(xp) : "v"(xs0));
  }
  if (wv < 2) {    // preload c0 fragments (rows row0 + wv*16 + fcol)
    const u16* ap = cbuf + (size_t)(row0 + wv * 16 + fcol) * 1024 + kofs;
#pragma unroll
    for (int kt = 0; kt < 32; ++kt)
      asm volatile("global_load_dwordx4 %0, %1, off sc0 sc1"
                   : "=v"(av[kt]) : "v"(ap + kt * 32));
  }
  WAIT_VM0();
  __syncthreads();

  for (int t = 0; t < NT; ++t) {
    float zo_reg, xres, hv;
    const size_t xo = (size_t)brow * (512 * 1024) + (size_t)t * 1024 + u;

    // ===== phase 1: waves 2-3 load h + z=h@R; waves 0-1 peephole from regs =====
    if (wv >= 2) {
      const int rt = wv - 2;
      const u16* ap = hbuf + (size_t)(row0 + rt * 16 + fcol) * 1024 + kofs;
#pragma unroll
      for (int kt = 0; kt < 32; ++kt)
        asm volatile("global_load_dwordx4 %0, %1, off sc0 sc1"
                     : "=v"(av[kt]) : "v"(ap + kt * 32));
      WAIT_VM0();
      f32x4 accA = {0.f, 0.f, 0.f, 0.f}, accB = {0.f, 0.f, 0.f, 0.f};
      const u16* bp0 = &wlds[fcol][kofs];
      const u16* bp1 = &wlds[16 + fcol][kofs];
#pragma unroll
      for (int kt = 0; kt < 32; ++kt) {
        accA = mfma16(av[kt], *(const s16x8*)(bp0 + kt * 32), accA);
        accB = mfma16(av[kt], *(const s16x8*)(bp1 + kt * 32), accB);
      }
      const int srow = rt * 16 + (lane >> 4) * 4;
#pragma unroll
      for (int q = 0; q < 4; ++q) {
        zlds[srow + q][fcol] = accA[q];
        zlds[srow + q][16 + fcol] = accB[q];
      }
    } else {
      f32x4 accP = {0.f, 0.f, 0.f, 0.f};
      const u16* bp = &wlds[32 + fcol][kofs];
#pragma unroll
      for (int kt = 0; kt < 32; ++kt)
        accP = mfma16(av[kt], *(const s16x8*)(bp + kt * 32), accP);
      const int srow = wv * 16 + (lane >> 4) * 4;
#pragma unroll
      for (int q = 0; q < 4; ++q) plds[srow + q][fcol] = accP[q];
    }
    __syncthreads();
    {
      // gate math — xwp/xp were prefetched last phase 2 and are already drained
      const float xw_i = bf2f((u16)(xwp[0] & 0xffffu));
      const float xw_f = bf2f((u16)(xwp[0] >> 16));
      const float xw_c = bf2f((u16)(xwp[1] & 0xffffu));
      const float xw_o = bf2f((u16)(xwp[1] >> 16));
      xres = xp;
      const float zi = zlds[r][ul]      + xw_i + b_i + plds[r][ul];
      const float zf = zlds[r][8 + ul]  + xw_f + b_f + plds[r][8 + ul];
      const float zc = zlds[r][16 + ul] + xw_c + b_c;
      zo_reg         = zlds[r][24 + ul] + xw_o + b_o;
      const float ig = hsig(zi), fg = hsig(zf);
      cst = fg * cst + ig * tanhf(zc);
      const float th = tanhf(cst);
      const unsigned int cb = f2bf(cst), tb = f2bf(th);
      const unsigned int cpart = (unsigned int)__shfl_xor((int)cb, 1);
      const unsigned int tpart = (unsigned int)__shfl_xor((int)tb, 1);
      if ((ul & 1) == 0) {
        atomic_swap_u32((unsigned int*)(cbuf + brow * 1024 + u), (cpart << 16) | cb);
        atomic_swap_u32((unsigned int*)(thbuf + brow * 1024 + u), (tpart << 16) | tb);
      }
    }
    WAIT_VM0();
    gbar(flags, bid, tid, 2 * t + 1);   // c_new / tanh(c_new) published (at L3)

    // ===== phase 2: o = hsig(zo + c_new@Po); h = o*(tanh(c_new)@proj + x_t) =====
    {
      const int prt = wv & 1;
      const u16* ap = ((wv < 2) ? (const u16*)cbuf : (const u16*)thbuf)
                      + (size_t)(row0 + prt * 16 + fcol) * 1024 + kofs;
#pragma unroll
      for (int kt = 0; kt < 32; ++kt)
        asm volatile("global_load_dwordx4 %0, %1, off sc0 sc1"
                     : "=v"(av[kt]) : "v"(ap + kt * 32));
      // prefetch next step's xw/x; stays in flight through MFMA + h-math
      {
        const int tn = (t + 1 < NT) ? (t + 1) : t;
        const u16* xrn = xw + (((size_t)ugrp * 512 + tn) * 64 + brow) * 32 + ul * 4;
        asm volatile("global_load_dwordx2 %0, %1, off" : "=v"(xwp) : "v"(xrn));
        const float* xsn = x + (size_t)brow * (512 * 1024) + (size_t)tn * 1024 + u;
        asm volatile("global_load_dword %0, %1, off" : "=v"(xp) : "v"(xsn));
      }
      asm volatile("s_waitcnt vmcnt(2)" ::: "memory");   // A-loads done; prefetch flying
      __builtin_amdgcn_sched_barrier(0);
      f32x4 acc = {0.f, 0.f, 0.f, 0.f};
      const u16* bp = &wlds[48 + fcol][kofs];   // cols 0-7 Po, 8-15 proj
#pragma unroll
      for (int kt = 0; kt < 32; ++kt)
        acc = mfma16(av[kt], *(const s16x8*)(bp + kt * 32), acc);
      const int srow = prt * 16 + (lane >> 4) * 4;
      if (wv < 2) {        // A = c_new -> Po result valid on cols 0-7
        if (fcol < 8) {
#pragma unroll
          for (int q = 0; q < 4; ++q) olds[srow + q][fcol] = acc[q];
        }
      } else {             // A = tanh(c_new) -> proj result valid on cols 8-15
        if (fcol >= 8) {
#pragma unroll
          for (int q = 0; q < 4; ++q) olds[srow + q][fcol] = acc[q];
        }
      }
    }
    __syncthreads();
    {
      const float og = hsig(zo_reg + olds[r][ul]);
      const float pv = olds[r][8 + ul] + xres;
      hv = og * pv;
      const unsigned int hb = f2bf(hv);
      const unsigned int hpart = (unsigned int)__shfl_xor((int)hb, 1);
      if ((ul & 1) == 0)
        atomic_swap_u32((unsigned int*)(hbuf + brow * 1024 + u), (hpart << 16) | hb);
    }
    WAIT_VM0();            // h atomic acked (also drains the xw/x prefetch)
    gbar(flags, bid, tid, 2 * t + 2);   // h published (at L3)
    // out store AFTER the barrier: drains during next step's phase 1
    asm volatile("global_store_dword %0, %1, off" :: "v"(out + xo), "v"(hv) : "memory");
  }
}

// ---------------------------------------------------------------------------
// Host launcher
// ---------------------------------------------------------------------------
extern "C" void kernel_launch(void* const* d_in, const int* in_sizes, int n_in,
                              void* d_out, int out_size, void* d_ws, size_t ws_size,
                              hipStream_t stream) {
  const float* x    = (const float*)d_in[0];
  const float* h0   = (const float*)d_in[1];
  const float* c0   = (const float*)d_in[2];
  const float* W    = (const float*)d_in[3];
  const float* R    = (const float*)d_in[4];
  const float* P    = (const float*)d_in[5];
  const float* PRJ  = (const float*)d_in[6];
  const float* bias = (const float*)d_in[7];
  float* out = (float*)d_out;
  char* ws = (char*)d_ws;

  const size_t XW_BYTES = (size_t)32768 * 4096 * 2;   // 268435456
  size_t off = XW_BYTES;
  u16* xw   = (u16*)ws;
  u16* hbuf = (u16*)(ws + off); off += 131072;
  u16* cbuf = (u16*)(ws + off); off += 131072;
  u16* thb  = (u16*)(ws + off); off += 131072;
  unsigned int* flags = (unsigned int*)(ws + off); off += 16384;
  if (ws_size < off) return;

  (void)hipFuncSetAttribute(reinterpret_cast<const void*>(&lstm_loop),
                            hipFuncAttributeMaxDynamicSharedMemorySize, 160 * 1024);

  hipMemsetAsync(flags, 0, 16384, stream);
  hipLaunchKernelGGL(init_comm, dim3(256), dim3(256), 0, stream, h0, c0, hbuf, cbuf);
  hipLaunchKernelGGL(xw_gemm, dim3(8192), dim3(256), 0, stream, x, W, xw);

  void* args[12];
  args[0] = (void*)&R;    args[1] = (void*)&P;     args[2] = (void*)&PRJ;
  args[3] = (void*)&bias; args[4] = (void*)&x;     args[5] = (void*)&xw;
  args[6] = (void*)&out;  args[7] = (void*)&hbuf;  args[8] = (void*)&cbuf;
  args[9] = (void*)&thb;  args[10] = (void*)&flags; args[11] = (void*)&c0;

  hipError_t e = hipLaunchCooperativeKernel((const void*)lstm_loop, dim3(256), dim3(256),
                                            args, (unsigned int)SMEM_B, stream);
  if (e != hipSuccess) {
    hipLaunchKernelGGL(lstm_loop, dim3(256), dim3(256), SMEM_B, stream,
                       R, P, PRJ, bias, x, xw, out, hbuf, cbuf, thb, flags, c0);
  }
}